// Round 8
// baseline (63.478 us; speedup 1.0000x reference)
//
#include <hip/hip_runtime.h>
#include <stdint.h>

// TopKLayer quirky sparse_hw: per row (3136 elems), t = spatial index of the
// k-th largest |x| (k=313, ties ascending index); keep the t smallest-|x|
// elements (stable). ONE WAVE PER ROW, ZERO barriers: row in registers
// (49 words/lane), per-wave private LDS slice. Packed-u16 2048-bin histogram
// (pad every 16 words -> conflict-free), CDF pulled into registers, O(1)
// locate, scan-based candidate compaction, 256-bin sub-hist rank.

#define HW     3136
#define NT     128       // 2 independent waves per block
#define WPB    2
#define KSEL   313u
#define CAP    448       // candidate bin capacity (stat max ~235+6sigma)
#define CAP2   64        // tie-set capacity
#define SLICE  1088      // words per wave slice (1024 packed + 64 pad)
#define O_CAND 0
#define O_HC   448
#define O_TINY 704
#define M31    0x7fffffffu

__device__ __forceinline__ unsigned wscan_incl(unsigned v) {
    const int lane = threadIdx.x & 63;
#pragma unroll
    for (int d = 1; d < 64; d <<= 1) {
        unsigned o = __shfl_up(v, d, 64);
        if (lane >= d) v += o;
    }
    return v;
}

__device__ __forceinline__ unsigned bcast_first(unsigned flag, unsigned val) {
    unsigned long long bal = __ballot(flag != 0);
    int fl = __ffsll(bal) - 1;
    return __shfl(val, fl, 64);
}

// packed u16 histogram add; word = bin>>1, padded index = word + word/16
__device__ __forceinline__ void hadd(unsigned* h, unsigned b) {
    atomicAdd(&h[(b >> 1) + (b >> 5)], (b & 1) ? 0x10000u : 1u);
}

// dir-rank `rank` over the row -> exact 31-bit key + spatial index.
// pc[16]: lane's packed counts for bins 32*lane..32*lane+31; base: excl CDF.
template <bool fromTop>
__device__ __forceinline__ void wave_select(
        unsigned* sl, const unsigned* __restrict__ gx,
        const uint4* v, unsigned vx,
        const unsigned* pc, unsigned base,
        unsigned rank, unsigned& keyOut, unsigned& idxOut) {
    const int lane = threadIdx.x & 63;

    // locate bin via register CDF (O(1) per lane, 32 bins unrolled)
    unsigned packed1 = 0;
    {
        unsigned run = base;
#pragma unroll
        for (int i = 0; i < 32; ++i) {
            const unsigned cb = (i & 1) ? (pc[i >> 1] >> 16) : (pc[i >> 1] & 0xFFFFu);
            if (fromTop) {
                const unsigned suf = HW - run - cb;
                if (suf < rank && rank <= suf + cb)
                    packed1 = ((unsigned)(lane * 32 + i) << 16) | (rank - suf);
            } else {
                if (run < rank && rank <= run + cb)
                    packed1 = ((unsigned)(lane * 32 + i) << 16) | (rank - run);
            }
            run += cb;
        }
    }
    packed1 = bcast_first(packed1, packed1);
    const unsigned b0 = packed1 >> 16;
    const unsigned m1 = packed1 & 0xFFFFu;

    // count own candidates, scan for write positions (no atomics)
    unsigned cc = 0;
#pragma unroll
    for (int i = 0; i < 12; ++i) {
        cc += (((v[i].x & M31) >> 20) == b0);
        cc += (((v[i].y & M31) >> 20) == b0);
        cc += (((v[i].z & M31) >> 20) == b0);
        cc += (((v[i].w & M31) >> 20) == b0);
    }
    cc += (((vx & M31) >> 20) == b0);
    const unsigned cin = wscan_incl(cc);
    const unsigned cnt = __shfl(cin, 63, 64);
    bool fb = (cnt > CAP);
    unsigned result = 0;

    if (!fb) {
        unsigned pos = cin - cc;
#pragma unroll
        for (int i = 0; i < 12; ++i) {
            const unsigned i0 = 4u * (unsigned)(lane + 64 * i);
            unsigned k;
            k = v[i].x & M31; if ((k >> 20) == b0) sl[O_CAND + pos++] = ((k & 0xFFFFFu) << 12) | i0;
            k = v[i].y & M31; if ((k >> 20) == b0) sl[O_CAND + pos++] = ((k & 0xFFFFFu) << 12) | (i0 + 1u);
            k = v[i].z & M31; if ((k >> 20) == b0) sl[O_CAND + pos++] = ((k & 0xFFFFFu) << 12) | (i0 + 2u);
            k = v[i].w & M31; if ((k >> 20) == b0) sl[O_CAND + pos++] = ((k & 0xFFFFFu) << 12) | (i0 + 3u);
        }
        { const unsigned k = vx & M31;
          if ((k >> 20) == b0) sl[O_CAND + pos++] = ((k & 0xFFFFFu) << 12) | (3072u + (unsigned)lane); }

        // clear + build 256-bin sub-histogram (composite bits 31:24)
#pragma unroll
        for (int i = 0; i < 4; ++i) sl[O_HC + lane + 64 * i] = 0;
        for (unsigned i = lane; i < cnt; i += 64)
            atomicAdd(&sl[O_HC + (sl[O_CAND + i] >> 24)], 1u);

        // lane owns sub-bins 4lane..4lane+3; register CDF + O(1) locate
        unsigned hh[4];
#pragma unroll
        for (int i = 0; i < 4; ++i) hh[i] = sl[O_HC + 4 * lane + i];
        const unsigned s4 = hh[0] + hh[1] + hh[2] + hh[3];
        unsigned run2 = wscan_incl(s4) - s4;
        unsigned packed2 = 0;
#pragma unroll
        for (int i = 0; i < 4; ++i) {
            if (fromTop) {
                const unsigned suf = cnt - run2 - hh[i];
                if (suf < m1 && m1 <= suf + hh[i])
                    packed2 = ((unsigned)(4 * lane + i) << 16) | (m1 - suf);
            } else {
                if (run2 < m1 && m1 <= run2 + hh[i])
                    packed2 = ((unsigned)(4 * lane + i) << 16) | (m1 - run2);
            }
            run2 += hh[i];
        }
        packed2 = bcast_first(packed2, packed2);
        const unsigned b2 = packed2 >> 16;
        const unsigned m2 = packed2 & 0xFFFFu;

        // gather tie set (scan-based), rank within it (c2 == 1 common case)
        unsigned tc = 0;
        for (unsigned i = lane; i < cnt; i += 64) tc += ((sl[O_CAND + i] >> 24) == b2);
        const unsigned tincl = wscan_incl(tc);
        const unsigned c2 = __shfl(tincl, 63, 64);
        if (c2 > CAP2) fb = true;
        else {
            unsigned tpos = tincl - tc;
            for (unsigned i = lane; i < cnt; i += 64) {
                const unsigned cw = sl[O_CAND + i];
                if ((cw >> 24) == b2) sl[O_TINY + tpos++] = cw;
            }
            unsigned hitf = 0, resv = 0;
            if ((unsigned)lane < c2) {
                const unsigned ci = sl[O_TINY + lane];
                const unsigned di = fromTop ? (ci ^ 0xFFFu) : ci;
                unsigned r = 1;
                for (unsigned j = 0; j < c2; ++j) {
                    const unsigned dj = fromTop ? (sl[O_TINY + j] ^ 0xFFFu) : sl[O_TINY + j];
                    if (fromTop ? (dj > di) : (dj < di)) r++;
                }
                if (r == m2) { hitf = 1; resv = ci; }
            }
            result = bcast_first(hitf, resv);
        }
    }

    if (fb) {  // pathological fallback: bin-filtered counting rank via global
        unsigned hitf = 0, resv = 0;
        for (unsigned j = lane; j < HW; j += 64) {
            const unsigned k = gx[j] & M31;
            if ((k >> 20) != b0) continue;
            unsigned Ci = ((k & 0xFFFFFu) << 12) | j;
            if (fromTop) Ci ^= 0xFFFu;
            unsigned r = 1;
            for (unsigned j2 = 0; j2 < HW; ++j2) {
                const unsigned k2 = gx[j2] & M31;
                if ((k2 >> 20) != b0) continue;
                unsigned Cj = ((k2 & 0xFFFFFu) << 12) | j2;
                if (fromTop) Cj ^= 0xFFFu;
                if (fromTop ? (Cj > Ci) : (Cj < Ci)) r++;
            }
            if (r == m1) { hitf = 1; resv = ((k & 0xFFFFFu) << 12) | j; }
        }
        result = bcast_first(hitf, resv);
    }

    keyOut = (b0 << 20) | (result >> 12);
    idxOut = result & 0xFFFu;
}

extern "C" __global__ void __launch_bounds__(NT)
topk_kernel(const float* __restrict__ x, float* __restrict__ out) {
    __shared__ unsigned lds[WPB][SLICE];   // 8704 B/block
    const int lane = threadIdx.x & 63;
    const int w = threadIdx.x >> 6;
    const int row = blockIdx.x * WPB + w;
    unsigned* sl = lds[w];
    const uint4* __restrict__ xin4 = (const uint4*)(x + (size_t)row * HW);
    const unsigned* __restrict__ gx = (const unsigned*)xin4;
    uint4* __restrict__ xout4 = (uint4*)(out + (size_t)row * HW);
    unsigned* __restrict__ gout = (unsigned*)(out + (size_t)row * HW);

    // clear histogram slice (1088 = 64*17 words)
#pragma unroll
    for (int i = 0; i < 17; ++i) sl[lane + 64 * i] = 0;

    // load row into registers (coalesced: 12 uint4 + 1 word per lane)
    uint4 v[12];
#pragma unroll
    for (int i = 0; i < 12; ++i) v[i] = xin4[lane + 64 * i];
    const unsigned vx = gx[3072 + lane];

    // 2048-bin packed-u16 histogram (abs bits 30:20)
#pragma unroll
    for (int i = 0; i < 12; ++i) {
        hadd(sl, (v[i].x & M31) >> 20);
        hadd(sl, (v[i].y & M31) >> 20);
        hadd(sl, (v[i].z & M31) >> 20);
        hadd(sl, (v[i].w & M31) >> 20);
    }
    hadd(sl, (vx & M31) >> 20);

    // pull packed counts into registers: lane owns bins 32lane..32lane+31
    // (padded word addr = 17*lane + i -> stride 17, conflict-free)
    unsigned pc[16];
#pragma unroll
    for (int i = 0; i < 16; ++i) pc[i] = sl[lane * 17 + i];
    unsigned ssum = 0;
#pragma unroll
    for (int i = 0; i < 16; ++i) ssum += (pc[i] & 0xFFFFu) + (pc[i] >> 16);
    const unsigned base = wscan_incl(ssum) - ssum;   // excl CDF of bin 32*lane

    // Select A: KSEL-th largest -> spatial index tIdx (= keep count)
    unsigned KA, tIdx;
    wave_select<true>(sl, gx, v, vx, pc, base, KSEL, KA, tIdx);

    if (tIdx == 0) {   // keep nothing
        const uint4 z = make_uint4(0u, 0u, 0u, 0u);
#pragma unroll
        for (int i = 0; i < 12; ++i) xout4[lane + 64 * i] = z;
        gout[3072 + lane] = 0u;
        return;
    }

    // Select B: tIdx-th smallest -> threshold key KB, cutoff index eB
    unsigned KB, eB;
    wave_select<false>(sl, gx, v, vx, pc, base, tIdx, KB, eB);

    // mask + store from registers: keep = k < KB || (k == KB && idx <= eB)
#pragma unroll
    for (int i = 0; i < 12; ++i) {
        const unsigned i0 = 4u * (unsigned)(lane + 64 * i);
        uint4 o = v[i];
        unsigned k;
        k = o.x & M31; if (!(k < KB || (k == KB && i0      <= eB))) o.x = 0u;
        k = o.y & M31; if (!(k < KB || (k == KB && i0 + 1u <= eB))) o.y = 0u;
        k = o.z & M31; if (!(k < KB || (k == KB && i0 + 2u <= eB))) o.z = 0u;
        k = o.w & M31; if (!(k < KB || (k == KB && i0 + 3u <= eB))) o.w = 0u;
        xout4[lane + 64 * i] = o;
    }
    {
        const unsigned k = vx & M31;
        gout[3072 + lane] =
            (k < KB || (k == KB && (3072u + (unsigned)lane) <= eB)) ? vx : 0u;
    }
}

extern "C" void kernel_launch(void* const* d_in, const int* in_sizes, int n_in,
                              void* d_out, int out_size, void* d_ws, size_t ws_size,
                              hipStream_t stream) {
    const float* x = (const float*)d_in[0];
    float* out = (float*)d_out;
    const int rows = in_sizes[0] / HW;          // 8192
    topk_kernel<<<dim3(rows / WPB), dim3(NT), 0, stream>>>(x, out);
}